// Round 3
// baseline (144.953 us; speedup 1.0000x reference)
//
#include <hip/hip_runtime.h>
#include <hip/hip_bf16.h>

#define N 4096
#define NUM_LIGHTS 64
#define NSLICE 32                 // emitter slices per bounce
#define SLICE (N / NSLICE)        // 128 emitters per slice
#define EPSF 1e-8f
#define MIN_DECAY 1e-4f
#define INV_FALLOFF_MAX 1.0f

static __device__ __forceinline__ float bf2f(unsigned short u) {
  union { unsigned int i; float f; } c;
  c.i = ((unsigned int)u) << 16;
  return c.f;
}

// ---------------------------------------------------------------------------
// Runtime dtype detection. geovalues ~ U[0.1,1.0), 4096 elements.
// Read the first 1024 EVEN bf16 indices (bytes 0..4093, safe under either
// dtype). If data is bf16, all are true geovalues in [0.1,1). If data is
// fp32, even bf16 slots are the low mantissa halves of random floats —
// random 16-bit patterns, essentially never all in [0.04,1.1] as bf16.
// flag = 1 -> bf16 mode, 0 -> fp32 mode.
// ---------------------------------------------------------------------------
__global__ __launch_bounds__(256) void detect_kernel(
    const unsigned short* __restrict__ geo_raw, int* __restrict__ flag) {
  __shared__ int allok;
  int tid = threadIdx.x;
  if (tid == 0) allok = 1;
  __syncthreads();
  bool ok = true;
#pragma unroll
  for (int t = 0; t < 4; ++t) {
    int s = tid * 4 + t;                 // sample 0..1023
    float v = bf2f(geo_raw[2 * s]);      // even bf16 index
    if (!(v >= 0.04f && v <= 1.1f)) ok = false;  // NaN also fails -> fp32
  }
  if (!ok) allok = 0;                    // benign race, all writers write 0
  __syncthreads();
  if (tid == 0) *flag = allok;
}

// ---------------------------------------------------------------------------
// Pack per-point data into float4 tables (dtype-branched loads):
//   P1[j] = {mean, aeff_j}  aeff = s0*s1*geo*nf (= area_j/pi)
//   P2[j] = {normal, 0} ; EM[j]={emission,0} ; BR[j]={brdf,0} ; B0=EM
// ---------------------------------------------------------------------------
__global__ __launch_bounds__(256) void prep_kernel(
    const void* __restrict__ means, const void* __restrict__ geo,
    const void* __restrict__ scales, const void* __restrict__ normals,
    const void* __restrict__ nf, const void* __restrict__ emis,
    const void* __restrict__ brdf, const int* __restrict__ flag,
    float4* __restrict__ P1, float4* __restrict__ P2,
    float4* __restrict__ EM, float4* __restrict__ BR,
    float4* __restrict__ B0) {
  int i = blockIdx.x * 256 + threadIdx.x;
  if (i >= N) return;
  const bool b16 = (*flag != 0);
  auto ld = [&](const void* p, int idx) -> float {
    if (b16) return __bfloat162float(((const __hip_bfloat16*)p)[idx]);
    return ((const float*)p)[idx];
  };
  float mx = ld(means, 3 * i + 0);
  float my = ld(means, 3 * i + 1);
  float mz = ld(means, 3 * i + 2);
  float s0 = ld(scales, 3 * i + 0);
  float s1 = ld(scales, 3 * i + 1);
  float g  = ld(geo, i);
  float f  = ld(nf, i);
  P1[i] = make_float4(mx, my, mz, s0 * s1 * g * f);
  P2[i] = make_float4(ld(normals, 3 * i + 0), ld(normals, 3 * i + 1),
                      ld(normals, 3 * i + 2), 0.0f);
  float ex = ld(emis, 3 * i + 0);
  float ey = ld(emis, 3 * i + 1);
  float ez = ld(emis, 3 * i + 2);
  EM[i] = make_float4(ex, ey, ez, 0.0f);
  B0[i] = make_float4(ex, ey, ez, 0.0f);
  BR[i] = make_float4(ld(brdf, 3 * i + 0), ld(brdf, 3 * i + 1),
                      ld(brdf, 3 * i + 2), 0.0f);
}

// lane = receiver i (state in registers); j loops over a wave-uniform emitter
// slice (scalar loads through K$). Partials to part[(s*3+c)*N + i].
__global__ __launch_bounds__(256) void gather_kernel(
    const float4* __restrict__ P1, const float4* __restrict__ P2,
    const float4* __restrict__ B, float* __restrict__ part) {
  int i = blockIdx.x * 256 + threadIdx.x;
  int s = blockIdx.y;
  float4 p1 = P1[i];   // my mean
  float4 p2 = P2[i];   // my normal
  float ax = 0.f, ay = 0.f, az = 0.f;
  int j0 = s * SLICE;
#pragma unroll 8
  for (int jj = 0; jj < SLICE; ++jj) {
    int j = j0 + jj;                     // wave-uniform
    float4 e1 = P1[j];
    float4 e2 = P2[j];
    float4 eb = B[j];
    float dx = e1.x - p1.x;              // diff = emitter - receiver
    float dy = e1.y - p1.y;
    float dz = e1.z - p1.z;
    float d2 = dx * dx + dy * dy + dz * dz + EPSF;
    float r  = rsqrtf(d2);
    float r2 = r * r;                    // ~ 1/d2
    float fall = fminf(fmaxf(r2, MIN_DECAY), INV_FALLOFF_MAX);
    float di = dx * p2.x + dy * p2.y + dz * p2.z;   // diff . n_i
    float ci = fmaxf(di, 0.f);
    float dj = dx * e2.x + dy * e2.y + dz * e2.z;   // diff . n_j
    float cj = fmaxf(-dj, 0.f);
    // F = cos_i*cos_j*falloff*aeff ; self term j==i gives di=dj=0 -> w=0
    float w = ci * cj * r2 * fall * e1.w;
    ax += w * eb.x;
    ay += w * eb.y;
    az += w * eb.z;
  }
  part[(s * 3 + 0) * N + i] = ax;
  part[(s * 3 + 1) * N + i] = ay;
  part[(s * 3 + 2) * N + i] = az;
}

__global__ __launch_bounds__(256) void reduce_kernel(
    const float* __restrict__ part, const float4* __restrict__ EM,
    const float4* __restrict__ BR, float4* __restrict__ Bnext,
    void* __restrict__ out, const int* __restrict__ flag, int last) {
  int i = blockIdx.x * 256 + threadIdx.x;
  float ax = 0.f, ay = 0.f, az = 0.f;
#pragma unroll 8
  for (int s = 0; s < NSLICE; ++s) {
    ax += part[(s * 3 + 0) * N + i];
    ay += part[(s * 3 + 1) * N + i];
    az += part[(s * 3 + 2) * N + i];
  }
  float4 em = EM[i];
  float bx, by, bz;
  if (i >= N - NUM_LIGHTS) {             // lights only emit
    bx = em.x; by = em.y; bz = em.z;
  } else {
    float4 br = BR[i];
    bx = em.x + br.x * ax;
    by = em.y + br.y * ay;
    bz = em.z + br.z * az;
  }
  Bnext[i] = make_float4(bx, by, bz, 0.0f);
  if (last) {
    bx = fmaxf(bx, 0.f); by = fmaxf(by, 0.f); bz = fmaxf(bz, 0.f);
    if (*flag != 0) {
      __hip_bfloat16* o = (__hip_bfloat16*)out;
      o[3 * i + 0] = __float2bfloat16(bx);
      o[3 * i + 1] = __float2bfloat16(by);
      o[3 * i + 2] = __float2bfloat16(bz);
    } else {
      float* o = (float*)out;
      o[3 * i + 0] = bx;
      o[3 * i + 1] = by;
      o[3 * i + 2] = bz;
    }
  }
}

// ---------------------------------------------------------------------------
extern "C" void kernel_launch(void* const* d_in, const int* in_sizes, int n_in,
                              void* d_out, int out_size, void* d_ws, size_t ws_size,
                              hipStream_t stream) {
  const void* means   = d_in[0];
  const void* geo     = d_in[1];
  const void* scales  = d_in[2];
  // d_in[3] = rots (unused, API parity)
  const void* normals = d_in[4];
  const void* nf      = d_in[5];
  const void* emis    = d_in[6];
  const void* brdf    = d_in[7];
  // d_in[8] = is_light_source (unused: lights are the tail NUM_LIGHTS block)

  char* ws = (char*)d_ws;
  int*    flag = (int*)ws;    ws += 256;              // keep tables 16B-aligned
  float4* P1 = (float4*)ws;   ws += (size_t)N * 16;
  float4* P2 = (float4*)ws;   ws += (size_t)N * 16;
  float4* EM = (float4*)ws;   ws += (size_t)N * 16;
  float4* BR = (float4*)ws;   ws += (size_t)N * 16;
  float4* Ba = (float4*)ws;   ws += (size_t)N * 16;
  float4* Bb = (float4*)ws;   ws += (size_t)N * 16;
  float*  part = (float*)ws;  // NSLICE*3*N floats = 1.5 MB

  detect_kernel<<<1, 256, 0, stream>>>((const unsigned short*)geo, flag);
  prep_kernel<<<N / 256, 256, 0, stream>>>(means, geo, scales, normals, nf,
                                           emis, brdf, flag, P1, P2, EM, BR, Ba);
  float4* cur = Ba;
  float4* nxt = Bb;
  for (int b = 0; b < 3; ++b) {
    gather_kernel<<<dim3(N / 256, NSLICE), 256, 0, stream>>>(P1, P2, cur, part);
    reduce_kernel<<<N / 256, 256, 0, stream>>>(part, EM, BR, nxt, d_out, flag,
                                               b == 2);
    float4* t = cur; cur = nxt; nxt = t;
  }
}

// Round 4
// 125.399 us; speedup vs baseline: 1.1559x; 1.1559x over previous
//
#include <hip/hip_runtime.h>

#define N 4096
#define NUM_LIGHTS 64
#define NSLICE 64                 // emitter slices per bounce
#define SLICE (N / NSLICE)        // 64 emitters per slice
#define EPSF 1e-8f
#define MIN_DECAY 1e-4f
#define INV_FALLOFF_MAX 1.0f

// All inputs/outputs are fp32 (verified round 3: absmax 1.9e-6 via fp32 path).

// Packed per-point tables (interleaved so emitter loads share one base):
//   E[2j]   = {mean.x, mean.y, mean.z, aeff_j}   aeff = s0*s1*geo*nf (= area/pi)
//   E[2j+1] = {normal.x, normal.y, normal.z, 0}
//   EM[j] = emission, BR[j] = brdf, B0[j] = bounce-0 radiosity (= emission)
__global__ __launch_bounds__(256) void prep_kernel(
    const float* __restrict__ means, const float* __restrict__ geo,
    const float* __restrict__ scales, const float* __restrict__ normals,
    const float* __restrict__ nf, const float* __restrict__ emis,
    const float* __restrict__ brdf,
    float4* __restrict__ E, float4* __restrict__ EM,
    float4* __restrict__ BR, float4* __restrict__ B0) {
  int i = blockIdx.x * 256 + threadIdx.x;
  if (i >= N) return;
  float aeff = scales[3 * i + 0] * scales[3 * i + 1] * geo[i] * nf[i];
  E[2 * i + 0] = make_float4(means[3 * i + 0], means[3 * i + 1],
                             means[3 * i + 2], aeff);
  E[2 * i + 1] = make_float4(normals[3 * i + 0], normals[3 * i + 1],
                             normals[3 * i + 2], 0.0f);
  float4 em = make_float4(emis[3 * i + 0], emis[3 * i + 1], emis[3 * i + 2], 0.0f);
  EM[i] = em;
  B0[i] = em;
  BR[i] = make_float4(brdf[3 * i + 0], brdf[3 * i + 1], brdf[3 * i + 2], 0.0f);
}

// lane = receiver i (state in registers); j loops over a wave-uniform emitter
// slice -> scalar loads through K$. Partials to part[(s*3+c)*N + i].
// grid (16, 64) = 1024 blocks -> 4 waves/SIMD.
__global__ __launch_bounds__(256) void gather_kernel(
    const float4* __restrict__ E, const float4* __restrict__ B,
    float* __restrict__ part) {
  int i = blockIdx.x * 256 + threadIdx.x;
  int s = blockIdx.y;
  float4 p1 = E[2 * i + 0];   // my mean
  float4 p2 = E[2 * i + 1];   // my normal
  float ax = 0.f, ay = 0.f, az = 0.f;
  int j0 = s * SLICE;
#pragma unroll 8
  for (int jj = 0; jj < SLICE; ++jj) {
    int j = j0 + jj;                     // wave-uniform
    float4 e1 = E[2 * j + 0];
    float4 e2 = E[2 * j + 1];
    float4 eb = B[j];
    float dx = e1.x - p1.x;              // diff = emitter - receiver
    float dy = e1.y - p1.y;
    float dz = e1.z - p1.z;
    float d2 = fmaf(dx, dx, fmaf(dy, dy, fmaf(dz, dz, EPSF)));
    float inv = __builtin_amdgcn_rcpf(d2);            // ~1/d2
    float fall = fminf(fmaxf(inv, MIN_DECAY), INV_FALLOFF_MAX);
    float di = fmaf(dx, p2.x, fmaf(dy, p2.y, dz * p2.z));   // diff . n_i
    float dj = fmaf(dx, e2.x, fmaf(dy, e2.y, dz * e2.z));   // diff . n_j
    // cos_i*cos_j/d2 = relu(di)*relu(-dj)*inv ; F = that * fall * aeff_j
    // self term j==i: diff=0 -> di=dj=0 -> w=0 automatically
    float w = fmaxf(di, 0.f) * fmaxf(-dj, 0.f) * inv * fall * e1.w;
    ax = fmaf(w, eb.x, ax);
    ay = fmaf(w, eb.y, ay);
    az = fmaf(w, eb.z, az);
  }
  part[(s * 3 + 0) * N + i] = ax;
  part[(s * 3 + 1) * N + i] = ay;
  part[(s * 3 + 2) * N + i] = az;
}

__global__ __launch_bounds__(256) void reduce_kernel(
    const float* __restrict__ part, const float4* __restrict__ EM,
    const float4* __restrict__ BR, float4* __restrict__ Bnext,
    float* __restrict__ out, int last) {
  int i = blockIdx.x * 256 + threadIdx.x;
  float ax = 0.f, ay = 0.f, az = 0.f;
#pragma unroll 4
  for (int s = 0; s < NSLICE; ++s) {
    ax += part[(s * 3 + 0) * N + i];
    ay += part[(s * 3 + 1) * N + i];
    az += part[(s * 3 + 2) * N + i];
  }
  float4 em = EM[i];
  float bx, by, bz;
  if (i >= N - NUM_LIGHTS) {             // lights only emit
    bx = em.x; by = em.y; bz = em.z;
  } else {
    float4 br = BR[i];
    bx = fmaf(br.x, ax, em.x);
    by = fmaf(br.y, ay, em.y);
    bz = fmaf(br.z, az, em.z);
  }
  Bnext[i] = make_float4(bx, by, bz, 0.0f);
  if (last) {
    out[3 * i + 0] = fmaxf(bx, 0.f);
    out[3 * i + 1] = fmaxf(by, 0.f);
    out[3 * i + 2] = fmaxf(bz, 0.f);
  }
}

extern "C" void kernel_launch(void* const* d_in, const int* in_sizes, int n_in,
                              void* d_out, int out_size, void* d_ws, size_t ws_size,
                              hipStream_t stream) {
  const float* means   = (const float*)d_in[0];
  const float* geo     = (const float*)d_in[1];
  const float* scales  = (const float*)d_in[2];
  // d_in[3] = rots (unused, API parity)
  const float* normals = (const float*)d_in[4];
  const float* nf      = (const float*)d_in[5];
  const float* emis    = (const float*)d_in[6];
  const float* brdf    = (const float*)d_in[7];
  // d_in[8] = is_light_source (unused: lights are the tail NUM_LIGHTS block)

  char* ws = (char*)d_ws;
  float4* E  = (float4*)ws;   ws += (size_t)N * 32;   // interleaved mean/normal
  float4* EM = (float4*)ws;   ws += (size_t)N * 16;
  float4* BR = (float4*)ws;   ws += (size_t)N * 16;
  float4* Ba = (float4*)ws;   ws += (size_t)N * 16;
  float4* Bb = (float4*)ws;   ws += (size_t)N * 16;
  float*  part = (float*)ws;  // NSLICE*3*N floats = 3 MB

  prep_kernel<<<N / 256, 256, 0, stream>>>(means, geo, scales, normals, nf,
                                           emis, brdf, E, EM, BR, Ba);
  float4* cur = Ba;
  float4* nxt = Bb;
  for (int b = 0; b < 3; ++b) {
    gather_kernel<<<dim3(N / 256, NSLICE), 256, 0, stream>>>(E, cur, part);
    reduce_kernel<<<N / 256, 256, 0, stream>>>(part, EM, BR, nxt,
                                               (float*)d_out, b == 2);
    float4* t = cur; cur = nxt; nxt = t;
  }
}